// Round 9
// baseline (2100.002 us; speedup 1.0000x reference)
//
#include <hip/hip_runtime.h>

// LSNN: B=64, T=1024, I=128, H=512, O=10
// d_in: x[64,1024,128], Wi[512,128], bi[512], Wr[512,512], Wo[10,512], bo[10] (f32)
// d_out: output[64,10] (640 floats) ++ hidden_states[64,1024,512] (spikes, f32)
//
// Numerics (FROZEN -- rounds 3/4/6/8 passed with absmax 0.0, bitwise):
//  - x_proj: np.einsum SSE emulation (4-lane acc, unfused mul+add, hsum, +bi).
//  - spikes@Wr: ascending-j add chain, rec = chain(j<384) + chain(j>=384).
//  - h = (ALPHA*h) + (xp + rec), each op separately rounded.
//
// Scan: 256 blocks = 8 column-slices x 32 sample-pairs; Wr slice [512][64] in
// LDS; per-step 512-bit spike masks via d_ws {mask,seq} records (sc0 sc1).
// THIS ROUND: (1) shuffle-free list build -- poll maps lane->slice(lane>>3),
// masks broadcast through a small LDS buffer, every lane computes k/kA/prefix
// locally (popcounts, no serial ds_bpermute chain); (2) list entries are
// pre-shifted row byte-offsets (j<<8) read as b128 quads; (3) 3-deep gather
// chunk pipeline. Gather order/adds bitwise-identical.

#define ALPHA_F 0.951229424500714f  // np.float32(exp(-0.05))

typedef unsigned int u32x4 __attribute__((ext_vector_type(4)));  // direct VGPR quad for asm

__device__ float g_mean[64 * 512];  // written before read each launch

// ---------------------------------------------------------------------------
// Kernel A: x_proj -- UNCHANGED (bitwise-verified).
// ---------------------------------------------------------------------------
__global__ __launch_bounds__(256) void xproj_kernel(
    const float* __restrict__ x, const float* __restrict__ Wi,
    const float* __restrict__ bi, float* __restrict__ out)
{
    __shared__ float xs[64][132];
    __shared__ float ws[32][132];

    const int tid = threadIdx.x;
    const int bm = blockIdx.x;
    const int bn = blockIdx.y;

    const float* xb = x  + (size_t)bm * 64 * 128;
    const float* wb = Wi + (size_t)bn * 32 * 128;

    for (int l = 0; l < 8; ++l) {
        int idx = l * 256 + tid;
        int row = idx >> 5, c4 = idx & 31;
        *(float4*)(&xs[row][c4 * 4]) = *(const float4*)(xb + row * 128 + c4 * 4);
    }
    for (int l = 0; l < 4; ++l) {
        int idx = l * 256 + tid;
        int row = idx >> 5, c4 = idx & 31;
        *(float4*)(&ws[row][c4 * 4]) = *(const float4*)(wb + row * 128 + c4 * 4);
    }
    __syncthreads();

    const int txh = tid & 15, txm = tid >> 4;
    const int m0 = txm * 4, h0 = txh * 2;

    float4 acc[4][2];
    #pragma unroll
    for (int mm = 0; mm < 4; ++mm)
        #pragma unroll
        for (int q = 0; q < 2; ++q)
            acc[mm][q] = make_float4(0.f, 0.f, 0.f, 0.f);

    for (int k4 = 0; k4 < 32; ++k4) {
        float4 a[4], b[2];
        #pragma unroll
        for (int mm = 0; mm < 4; ++mm) a[mm] = *(const float4*)(&xs[m0 + mm][k4 * 4]);
        #pragma unroll
        for (int q = 0; q < 2; ++q)    b[q]  = *(const float4*)(&ws[h0 + q][k4 * 4]);
        #pragma unroll
        for (int mm = 0; mm < 4; ++mm) {
            #pragma unroll
            for (int q = 0; q < 2; ++q) {
                float p0 = a[mm].x * b[q].x;
                float p1 = a[mm].y * b[q].y;
                float p2 = a[mm].z * b[q].z;
                float p3 = a[mm].w * b[q].w;
                asm volatile("" : "+v"(p0), "+v"(p1), "+v"(p2), "+v"(p3));
                acc[mm][q].x += p0;
                acc[mm][q].y += p1;
                acc[mm][q].z += p2;
                acc[mm][q].w += p3;
            }
        }
    }

    const int hbase = bn * 32 + h0;
    #pragma unroll
    for (int mm = 0; mm < 4; ++mm) {
        size_t m = (size_t)bm * 64 + m0 + mm;
        float2 o;
        {
            float s01 = acc[mm][0].x + acc[mm][0].y;
            float s23 = acc[mm][0].z + acc[mm][0].w;
            float hs  = s01 + s23;
            o.x = hs + bi[hbase + 0];
        }
        {
            float s01 = acc[mm][1].x + acc[mm][1].y;
            float s23 = acc[mm][1].z + acc[mm][1].w;
            float hs  = s01 + s23;
            o.y = hs + bi[hbase + 1];
        }
        *(float2*)(&out[m * 512 + hbase]) = o;
    }
}

// ---------------------------------------------------------------------------
// Kernel B: LIF scan, 8 slice-blocks per sample, Wr slice in LDS.
// ---------------------------------------------------------------------------
struct C8 { float a, b, c, d, e, f, g, h; };

// list entries are row byte-offsets (j<<8); chunk read = 2 x b128 (uniform).
__device__ __forceinline__ C8 fetch8v(const unsigned int* lst, int cidx,
                                      const char* wbase, int lane4) {
    u32x4 L0 = *(const u32x4*)(lst + cidx * 8);
    u32x4 L1 = *(const u32x4*)(lst + cidx * 8 + 4);
    C8 r;
    r.a = *(const float*)(wbase + (L0.x + lane4));
    r.b = *(const float*)(wbase + (L0.y + lane4));
    r.c = *(const float*)(wbase + (L0.z + lane4));
    r.d = *(const float*)(wbase + (L0.w + lane4));
    r.e = *(const float*)(wbase + (L1.x + lane4));
    r.f = *(const float*)(wbase + (L1.y + lane4));
    r.g = *(const float*)(wbase + (L1.z + lane4));
    r.h = *(const float*)(wbase + (L1.w + lane4));
    return r;
}

// consume entries [e, e+8) ascending; split chains at kA (uniform). FROZEN.
__device__ __forceinline__ void consume8(const C8& v, int e, int kA, int k,
                                         float& recA, float& recB) {
    if (e + 8 <= kA) {
        recA += v.a; recA += v.b; recA += v.c; recA += v.d;
        recA += v.e; recA += v.f; recA += v.g; recA += v.h;
    } else if (e >= kA && e + 8 <= k) {
        recB += v.a; recB += v.b; recB += v.c; recB += v.d;
        recB += v.e; recB += v.f; recB += v.g; recB += v.h;
    } else {
        if (e + 0 < k) { if (e + 0 < kA) recA += v.a; else recB += v.a; }
        if (e + 1 < k) { if (e + 1 < kA) recA += v.b; else recB += v.b; }
        if (e + 2 < k) { if (e + 2 < kA) recA += v.c; else recB += v.c; }
        if (e + 3 < k) { if (e + 3 < kA) recA += v.d; else recB += v.d; }
        if (e + 4 < k) { if (e + 4 < kA) recA += v.e; else recB += v.e; }
        if (e + 5 < k) { if (e + 5 < kA) recA += v.f; else recB += v.f; }
        if (e + 6 < k) { if (e + 6 < kA) recA += v.g; else recB += v.g; }
        if (e + 7 < k) { if (e + 7 < kA) recA += v.h; else recB += v.h; }
    }
}

__global__ __launch_bounds__(128, 1) void scan_kernel(
    const float* __restrict__ Wr, float* __restrict__ hid,
    u32x4* __restrict__ syn)
{
    const int blk  = blockIdx.x;    // 0..255
    const int p    = blk & 31;      // sample pair (slices of a pair share an XCD)
    const int c    = blk >> 5;      // column slice 0..7
    const int tid  = threadIdx.x;   // 0..127
    const int w    = tid >> 6;      // wave -> sample select
    const int lane = tid & 63;
    const int s    = p + 32 * w;    // sample
    const int n    = (c << 6) + lane;
    const int lane4 = lane << 2;

    __shared__ float wrs[512][64];                 // Wr[:, c*64 .. +64) : 128 KB
    __shared__ alignas(16) unsigned int lists[2][512];   // entries = j<<8
    __shared__ alignas(16) unsigned int maskbuf[2][16];  // 8 slices x 2 dwords, per wave

    #pragma unroll
    for (int i = 0; i < 8; ++i) ((unsigned int*)lists)[i * 128 + tid] = 0;

    {   // load Wr slice into LDS (coalesced 256B row segments)
        const float* src = Wr + (c << 6);
        for (int it = 0; it < 64; ++it) {
            int idx = it * 128 + tid;      // 0..8191 float4s
            int r = idx >> 4, q = idx & 15;
            float4 v = *(const float4*)(src + (size_t)r * 512 + q * 4);
            *(float4*)(&wrs[r][q * 4]) = v;
        }
    }
    __syncthreads();   // only barrier; waves are independent afterwards

    unsigned int* list = lists[w];
    const char* wbase = (const char*)&wrs[0][0];
    float* base = hid + ((size_t)s * 1024) * 512 + n;

    float hstate = 0.0f;
    int cnt = 0;
    float xp = base[0];

    // Probe quads: "+v" issue constraints keep these registers LIVE for the
    // whole loop (round-8 liveness fix) -- a stray in-flight probe can only
    // write its own pinned registers.
    u32x4 prb0 = {0, 0, 0, 0}, prb1 = {0, 0, 0, 0};

    for (int t = 0; t < 1024; ++t) {
        int k = 0, kA = 0;
        if (t > 0) {
            // lane L polls slice (L>>3)'s record -> own slice words land locally
            const u32x4* pp = syn + ((((t - 1) & 1) * 64 + s) * 8) + (lane >> 3);
            asm volatile("s_waitcnt vmcnt(0)" ::: "memory");  // pre-drain
            u32x4 pv;
            asm volatile("global_load_dwordx4 %0, %2, off sc0 sc1\n\t"
                         "global_load_dwordx4 %1, %2, off sc0 sc1"
                         : "+v"(prb0), "+v"(prb1) : "v"(pp) : "memory");
            for (;;) {
                asm volatile("s_waitcnt vmcnt(1)" : "+v"(prb0) :: "memory");
                unsigned long long ok = __ballot(prb0.z == (unsigned)t);
                if (ok == ~0ull) { pv = prb0; break; }
                asm volatile("global_load_dwordx4 %0, %1, off sc0 sc1"
                             : "+v"(prb0) : "v"(pp) : "memory");
                asm volatile("s_waitcnt vmcnt(1)" : "+v"(prb1) :: "memory");
                ok = __ballot(prb1.z == (unsigned)t);
                if (ok == ~0ull) { pv = prb1; break; }
                asm volatile("global_load_dwordx4 %0, %1, off sc0 sc1"
                             : "+v"(prb1) : "v"(pp) : "memory");
            }

            // broadcast the 8 masks through LDS (one writer lane per slice)
            if ((lane & 7) == 0) {
                unsigned long long mword =
                    (((unsigned long long)pv.y) << 32) | (unsigned long long)pv.x;
                *(unsigned long long*)&maskbuf[w][(lane >> 3) * 2] = mword;
            }
            u32x4 r0 = *(const u32x4*)&maskbuf[w][0];
            u32x4 r1 = *(const u32x4*)&maskbuf[w][4];
            u32x4 r2 = *(const u32x4*)&maskbuf[w][8];
            u32x4 r3 = *(const u32x4*)&maskbuf[w][12];

            // per-dword popcounts (dword i = global bits [32i, 32i+32))
            int p0 = __popc(r0.x), p1 = __popc(r0.y), p2 = __popc(r0.z), p3 = __popc(r0.w);
            int p4 = __popc(r1.x), p5 = __popc(r1.y), p6 = __popc(r1.z), p7 = __popc(r1.w);
            int p8 = __popc(r2.x), p9 = __popc(r2.y), p10 = __popc(r2.z), p11 = __popc(r2.w);
            int p12 = __popc(r3.x), p13 = __popc(r3.y), p14 = __popc(r3.z), p15 = __popc(r3.w);
            int ka_ = p0 + p1 + p2 + p3 + p4 + p5 + p6 + p7 + p8 + p9 + p10 + p11;
            int k_  = ka_ + p12 + p13 + p14 + p15;   // j<384 <=> dwords 0..11
            kA = __builtin_amdgcn_readfirstlane(ka_);
            k  = __builtin_amdgcn_readfirstlane(k_);

            // lane L owns global bits [8L, 8L+8): prefix = popcount below 8L
            const int myW = lane >> 2;               // dword index 0..15
            int pre = 0;
            if (myW >  0) pre += p0;   if (myW >  1) pre += p1;
            if (myW >  2) pre += p2;   if (myW >  3) pre += p3;
            if (myW >  4) pre += p4;   if (myW >  5) pre += p5;
            if (myW >  6) pre += p6;   if (myW >  7) pre += p7;
            if (myW >  8) pre += p8;   if (myW >  9) pre += p9;
            if (myW > 10) pre += p10;  if (myW > 11) pre += p11;
            if (myW > 12) pre += p12;  if (myW > 13) pre += p13;
            if (myW > 14) pre += p14;
            unsigned word = (lane & 4) ? pv.y : pv.x;      // own dword (from probe)
            int shb = (lane & 3) * 8;
            pre += __popc(word & ((1u << shb) - 1u));
            unsigned byte = (word >> shb) & 0xFFu;

            // scatter ascending-j entries: j = lane*8 + bt, entry = j<<8
            int pos = pre;
            unsigned jbase = (unsigned)lane << 11;         // (lane*8)<<8
            while (byte) {
                int bt = __builtin_ctz(byte);
                byte &= byte - 1u;
                list[pos++] = jbase + ((unsigned)bt << 8);
            }
        }

        // xp prefetch after poll: hides under the gather, outside the poll wait
        float xp_next = base[(size_t)(t < 1023 ? t + 1 : 1023) * 512];

        float recA = 0.0f, recB = 0.0f;
        {
            int nch = (k + 7) >> 3;
            C8 b0, b1, b2;
            if (nch > 0) b0 = fetch8v(list, 0, wbase, lane4);
            if (nch > 1) b1 = fetch8v(list, 1, wbase, lane4);
            if (nch > 2) b2 = fetch8v(list, 2, wbase, lane4);
            int cc = 0;
            for (; cc + 6 <= nch; cc += 3) {
                consume8(b0, (cc + 0) * 8, kA, k, recA, recB); b0 = fetch8v(list, cc + 3, wbase, lane4);
                consume8(b1, (cc + 1) * 8, kA, k, recA, recB); b1 = fetch8v(list, cc + 4, wbase, lane4);
                consume8(b2, (cc + 2) * 8, kA, k, recA, recB); b2 = fetch8v(list, cc + 5, wbase, lane4);
            }
            int rem = nch - cc;   // 0..5
            if (rem >= 1) consume8(b0, (cc + 0) * 8, kA, k, recA, recB);
            if (rem >= 4) b0 = fetch8v(list, cc + 3, wbase, lane4);
            if (rem >= 2) consume8(b1, (cc + 1) * 8, kA, k, recA, recB);
            if (rem >= 5) b1 = fetch8v(list, cc + 4, wbase, lane4);
            if (rem >= 3) consume8(b2, (cc + 2) * 8, kA, k, recA, recB);
            if (rem >= 4) consume8(b0, (cc + 3) * 8, kA, k, recA, recB);
            if (rem >= 5) consume8(b1, (cc + 4) * 8, kA, k, recA, recB);
        }

        // state update (FROZEN semantics)
        float rec = recA + recB;        // kc-block join
        float cur = xp + rec;
        float tmp = ALPHA_F * hstate;
        asm volatile("" : "+v"(tmp));   // forbid fma contraction
        float hn = tmp + cur;
        bool sp = (hn >= 1.0f);
        hstate = sp ? 0.0f : hn;

        // publish own 64-bit mask FIRST (single 16B device-coherent store)
        unsigned long long bm = __ballot(sp);
        if (lane == 0) {
            u32x4 pk;
            pk.x = (unsigned)bm; pk.y = (unsigned)(bm >> 32);
            pk.z = (unsigned)(t + 1); pk.w = 0u;
            u32x4* qp = syn + (((t & 1) * 64 + s) * 8) + c;
            asm volatile("global_store_dwordx4 %0, %1, off sc0 sc1"
                         :: "v"(qp), "v"(pk) : "memory");
        }

        base[(size_t)t * 512] = sp ? 1.0f : 0.0f;
        cnt += sp ? 1 : 0;
        xp = xp_next;
    }

    // retire the final stray probe before its registers can be reused
    asm volatile("s_waitcnt vmcnt(0)" ::: "memory");
    asm volatile("" :: "v"(prb0), "v"(prb1));

    g_mean[s * 512 + n] = (float)cnt * (1.0f / 1024.0f);
}

// ---------------------------------------------------------------------------
// Kernel C: readout -- UNCHANGED.
// ---------------------------------------------------------------------------
__global__ __launch_bounds__(64) void readout_kernel(
    const float* __restrict__ Wo, const float* __restrict__ bo,
    float* __restrict__ out)
{
    const int b = blockIdx.x, o = blockIdx.y;
    const int lane = threadIdx.x;
    const float* mr = g_mean + b * 512;
    const float* wr = Wo + o * 512;
    double s = 0.0;
    for (int i = lane; i < 512; i += 64) s += (double)mr[i] * (double)wr[i];
    #pragma unroll
    for (int off = 32; off; off >>= 1) s += __shfl_down(s, off);
    if (lane == 0) out[b * 10 + o] = (float)(s + (double)bo[o]);
}

extern "C" void kernel_launch(void* const* d_in, const int* in_sizes, int n_in,
                              void* d_out, int out_size, void* d_ws, size_t ws_size,
                              hipStream_t stream) {
    const float* x  = (const float*)d_in[0];
    const float* Wi = (const float*)d_in[1];
    const float* bi = (const float*)d_in[2];
    const float* Wr = (const float*)d_in[3];
    const float* Wo = (const float*)d_in[4];
    const float* bo = (const float*)d_in[5];

    float* out = (float*)d_out;
    float* hid = out + 640;  // hidden_states region doubles as x_proj scratch

    // zero the mask-exchange records (2 slots x 64 samples x 8 slices x 16B)
    (void)hipMemsetAsync(d_ws, 0, 2 * 64 * 8 * 16, stream);

    dim3 gA(1024, 16);
    xproj_kernel<<<gA, 256, 0, stream>>>(x, Wi, bi, hid);

    scan_kernel<<<256, 128, 0, stream>>>(Wr, hid, (u32x4*)d_ws);

    dim3 gC(64, 10);
    readout_kernel<<<gC, 64, 0, stream>>>(Wo, bo, out);
}